// Round 8
// baseline (998.282 us; speedup 1.0000x reference)
//
#include <hip/hip_runtime.h>
#include <hip/hip_bf16.h>
#include <math.h>

#define S_LEN 4096
#define D_MODEL 768
#define NHEAD 12
#define DH 64
#define NLAYER 2
#define DFF 3072
#define BATCH 2
#define QSTR 2304   // fused QKV row stride

typedef __attribute__((ext_vector_type(8))) __bf16 bf16x8;
typedef __attribute__((ext_vector_type(4))) float f32x4;
typedef __attribute__((ext_vector_type(16))) float f32x16;

__device__ __forceinline__ unsigned short f2bf_bits(float f) {
  unsigned int u = __float_as_uint(f);
  unsigned int r = (u + 0x7fffu + ((u >> 16) & 1u)) >> 16;
  return (unsigned short)r;
}

__device__ __forceinline__ float bf2f(unsigned short u) {
  return __uint_as_float(((unsigned int)u) << 16);
}

__device__ __forceinline__ unsigned int cvtpk_bf16(float lo, float hi) {
  unsigned int d;
  asm("v_cvt_pk_bf16_f32 %0, %1, %2" : "=v"(d) : "v"(lo), "v"(hi));
  return d;
}

// tanh-gelu with cheap tanh via one __expf (clamped)
__device__ __forceinline__ float gelu_fast(float x) {
  float u = 0.7978845608028654f * (x + 0.044715f * x * x * x);
  float t2 = fminf(fmaxf(2.f * u, -18.f), 18.f);
  float e = __expf(t2);
  return 0.5f * x * (1.f + (e - 1.f) / (e + 1.f));
}

#define ASYNC_COPY16(gsrc, ldst)                                       \
  __builtin_amdgcn_global_load_lds(                                    \
      (const __attribute__((address_space(1))) void*)(gsrc),           \
      (__attribute__((address_space(3))) void*)(ldst), 16, 0, 0)

#define MFMA_BF16(a, b, c) __builtin_amdgcn_mfma_f32_16x16x32_bf16(a, b, c, 0, 0, 0)
#define MFMA32_BF16(a, b, c) __builtin_amdgcn_mfma_f32_32x32x16_bf16(a, b, c, 0, 0, 0)

// ---------------------------------------------------------------------------
__device__ __forceinline__ float blk_sum256(float v, float* lds) {
#pragma unroll
  for (int off = 32; off > 0; off >>= 1) v += __shfl_down(v, off, 64);
  __syncthreads();
  if ((threadIdx.x & 63) == 0) lds[threadIdx.x >> 6] = v;
  __syncthreads();
  return lds[0] + lds[1] + lds[2] + lds[3];
}

// ---------------------------------------------------------------------------
// weight transpose + fp32->bf16 convert: W[K][N] f32 -> Wt[N][K] bf16
// ---------------------------------------------------------------------------
__global__ __launch_bounds__(256) void wconv_kernel(
    const float* __restrict__ Wq, const float* __restrict__ Wk,
    const float* __restrict__ Wv, const float* __restrict__ Wo,
    const float* __restrict__ Wf1, const float* __restrict__ Wf2,
    unsigned short* __restrict__ Wbf) {
  int id = blockIdx.x;
  const float* src;
  unsigned short* dst;
  int K, N, t;
  if (id < 4608) {
    int m = id / 576;
    t = id % 576;
    int layer = m >> 2, which = m & 3;
    const float* s = (which == 0) ? Wq : (which == 1) ? Wk : (which == 2) ? Wv : Wo;
    src = s + (size_t)layer * 589824;
    dst = Wbf + (size_t)layer * 7077888 + (size_t)which * 589824;
    K = 768; N = 768;
  } else if (id < 9216) {
    int j = id - 4608;
    int layer = j / 2304;
    t = j % 2304;
    src = Wf1 + (size_t)layer * 2359296;
    dst = Wbf + (size_t)layer * 7077888 + 2359296;
    K = 768; N = 3072;
  } else {
    int j = id - 9216;
    int layer = j / 2304;
    t = j % 2304;
    src = Wf2 + (size_t)layer * 2359296;
    dst = Wbf + (size_t)layer * 7077888 + 4718592;
    K = 3072; N = 768;
  }
  int tiles_n = N >> 5;
  int tk = t / tiles_n, tn = t % tiles_n;
  __shared__ float tile[32][33];
  int c = threadIdx.x & 31, r0 = threadIdx.x >> 5;
#pragma unroll
  for (int p = 0; p < 4; ++p) {
    int r = r0 + p * 8;
    tile[r][c] = src[(size_t)(tk * 32 + r) * N + tn * 32 + c];
  }
  __syncthreads();
#pragma unroll
  for (int p = 0; p < 4; ++p) {
    int r = r0 + p * 8;
    dst[(size_t)(tn * 32 + r) * K + tk * 32 + c] = f2bf_bits(tile[c][r]);
  }
}

// ---------------------------------------------------------------------------
// embedding gather + LayerNorm -> bf16 Xb only
// ---------------------------------------------------------------------------
__global__ __launch_bounds__(256) void embed_ln_kernel(
    const int* __restrict__ ids, const float* __restrict__ wemb,
    const float* __restrict__ pemb, const float* __restrict__ g,
    const float* __restrict__ b, unsigned short* __restrict__ Xb) {
  int row = blockIdx.x;
  int s = row % S_LEN;
  int id = ids[row];
  const float* we = wemb + (size_t)id * D_MODEL;
  const float* pe = pemb + (size_t)s * D_MODEL;
  int t = threadIdx.x;
  __shared__ float lds[4];
  float v0 = we[t] + pe[t];
  float v1 = we[t + 256] + pe[t + 256];
  float v2 = we[t + 512] + pe[t + 512];
  float mean = blk_sum256(v0 + v1 + v2, lds) * (1.f / 768.f);
  float d0 = v0 - mean, d1 = v1 - mean, d2 = v2 - mean;
  float var = blk_sum256(d0 * d0 + d1 * d1 + d2 * d2, lds) * (1.f / 768.f);
  float rs = rsqrtf(var + 1e-5f);
  unsigned short* xb = Xb + (size_t)row * D_MODEL;
  xb[t]       = f2bf_bits(d0 * rs * g[t] + b[t]);
  xb[t + 256] = f2bf_bits(d1 * rs * g[t + 256] + b[t + 256]);
  xb[t + 512] = f2bf_bits(d2 * rs * g[t + 512] + b[t + 512]);
}

// ---------------------------------------------------------------------------
// LayerNorm: Xb = LN(T) * g + b  (T f32 in, bf16 out only)
// ---------------------------------------------------------------------------
__global__ __launch_bounds__(256) void ln_kernel(
    const float* __restrict__ T, const float* __restrict__ g,
    const float* __restrict__ b, unsigned short* __restrict__ Xb) {
  int row = blockIdx.x;
  const float* tp = T + (size_t)row * D_MODEL;
  int t = threadIdx.x;
  __shared__ float lds[4];
  float v0 = tp[t], v1 = tp[t + 256], v2 = tp[t + 512];
  float mean = blk_sum256(v0 + v1 + v2, lds) * (1.f / 768.f);
  float d0 = v0 - mean, d1 = v1 - mean, d2 = v2 - mean;
  float var = blk_sum256(d0 * d0 + d1 * d1 + d2 * d2, lds) * (1.f / 768.f);
  float rs = rsqrtf(var + 1e-5f);
  unsigned short* xb = Xb + (size_t)row * D_MODEL;
  xb[t]       = f2bf_bits(d0 * rs * g[t] + b[t]);
  xb[t + 256] = f2bf_bits(d1 * rs * g[t + 256] + b[t + 256]);
  xb[t + 512] = f2bf_bits(d2 * rs * g[t + 512] + b[t + 512]);
}

// ---------------------------------------------------------------------------
// 32x32x16-MFMA GEMM: 128x128 tile, BK=32, 4 waves (2x2), 3-buf counted
// vmcnt pipeline. C/D: col=lane&31, row=(reg&3)+8*(reg>>2)+4*(lane>>5).
// MODE 1: out bf16, +bias0, gelu           (FFN1)
// MODE 2: out f32, +bias0, +Res bf16       (O-proj / FFN2), N must be 768
// MODE 4: out bf16 stride N, 3 biases, cols<768 scaled 1/8 (QKV)
// ---------------------------------------------------------------------------
template <int MODE>
__global__ __launch_bounds__(256) void gemm32(
    const unsigned short* __restrict__ A, const unsigned short* __restrict__ Bt,
    const float* __restrict__ bias0, const float* __restrict__ bias1,
    const float* __restrict__ bias2, const unsigned short* __restrict__ ResBf,
    void* __restrict__ Cout, int M, int N, int K) {
  __shared__ unsigned short Abuf[3][128 * 32];
  __shared__ unsigned short Bbuf[3][128 * 32];
  const int tid = threadIdx.x;
  const int lane = tid & 63, w = tid >> 6;
  const int wm = w >> 1, wn = w & 1;
  const int l31 = lane & 31, l5 = lane >> 5;

  const int nbx = gridDim.x;
  const int nwg = nbx * gridDim.y;
  const int orig = blockIdx.y * nbx + blockIdx.x;
  const int wgid = (orig & 7) * (nwg >> 3) + (orig >> 3);
  const int m0 = (wgid / nbx) * 128, n0 = (wgid % nbx) * 128;

  f32x16 acc[2][2];
#pragma unroll
  for (int i = 0; i < 2; ++i)
#pragma unroll
    for (int j = 0; j < 2; ++j)
#pragma unroll
      for (int r = 0; r < 16; ++r) acc[i][j][r] = 0.f;

  const int s0 = w * 64 + lane, s1 = s0 + 256;
  const int r0 = s0 >> 2, c0 = (s0 & 3) ^ ((r0 >> 1) & 3);
  const int r1 = s1 >> 2, c1 = (s1 & 3) ^ ((r1 >> 1) & 3);
  const unsigned short* gA0 = A + (size_t)(m0 + r0) * K + c0 * 8;
  const unsigned short* gA1 = A + (size_t)(m0 + r1) * K + c1 * 8;
  const unsigned short* gB0 = Bt + (size_t)(n0 + r0) * K + c0 * 8;
  const unsigned short* gB1 = Bt + (size_t)(n0 + r1) * K + c1 * 8;
  const int dA0 = (w * 64) * 8, dA1 = (256 + w * 64) * 8;

  int aoff[2][2], boff[2][2];
#pragma unroll
  for (int mt = 0; mt < 2; ++mt) {
    int ra = wm * 64 + mt * 32 + l31;
    int rb = wn * 64 + mt * 32 + l31;
    int key_a = (ra >> 1) & 3, key_b = (rb >> 1) & 3;
#pragma unroll
    for (int ks = 0; ks < 2; ++ks) {
      aoff[mt][ks] = ra * 32 + ((((ks << 1) | l5) ^ key_a) << 3);
      boff[mt][ks] = rb * 32 + ((((ks << 1) | l5) ^ key_b) << 3);
    }
  }

#define STAGE(bsel)                                                       \
  {                                                                       \
    ASYNC_COPY16(gA0, &Abuf[bsel][dA0]);                                  \
    ASYNC_COPY16(gA1, &Abuf[bsel][dA1]);                                  \
    ASYNC_COPY16(gB0, &Bbuf[bsel][dA0]);                                  \
    ASYNC_COPY16(gB1, &Bbuf[bsel][dA1]);                                  \
    gA0 += 32; gA1 += 32; gB0 += 32; gB1 += 32;                           \
  }

  const int nk = K >> 5;
  STAGE(0);
  if (nk > 1) STAGE(1);
  asm volatile("s_waitcnt vmcnt(4)" ::: "memory");
  __builtin_amdgcn_s_barrier();
  __builtin_amdgcn_sched_barrier(0);

  int cur = 0;
  for (int kt = 0; kt < nk; ++kt) {
    if (kt + 2 < nk) {
      int nxt = cur + 2;
      if (nxt >= 3) nxt -= 3;
      STAGE(nxt);
    }
    bf16x8 av[2][2], bv[2][2];
#pragma unroll
    for (int mt = 0; mt < 2; ++mt)
#pragma unroll
      for (int ks = 0; ks < 2; ++ks) {
        av[mt][ks] = *(const bf16x8*)(&Abuf[cur][aoff[mt][ks]]);
        bv[mt][ks] = *(const bf16x8*)(&Bbuf[cur][boff[mt][ks]]);
      }
#pragma unroll
    for (int mt = 0; mt < 2; ++mt)
#pragma unroll
      for (int nt = 0; nt < 2; ++nt)
#pragma unroll
        for (int ks = 0; ks < 2; ++ks)
          acc[mt][nt] = MFMA32_BF16(av[mt][ks], bv[nt][ks], acc[mt][nt]);
    if (kt + 1 < nk) {
      if (kt + 2 < nk)
        asm volatile("s_waitcnt vmcnt(4)" ::: "memory");
      else
        asm volatile("s_waitcnt vmcnt(0)" ::: "memory");
      __builtin_amdgcn_s_barrier();
      __builtin_amdgcn_sched_barrier(0);
    }
    cur = (cur == 2) ? 0 : cur + 1;
  }
#undef STAGE

#pragma unroll
  for (int mt = 0; mt < 2; ++mt) {
#pragma unroll
    for (int nt = 0; nt < 2; ++nt) {
      int gc = n0 + wn * 64 + nt * 32 + l31;
      float bsv;
      if (MODE == 4)
        bsv = (gc < 768) ? bias0[gc] : (gc < 1536) ? bias1[gc - 768] : bias2[gc - 1536];
      else
        bsv = bias0[gc];
#pragma unroll
      for (int reg = 0; reg < 16; ++reg) {
        int gr = m0 + wm * 64 + mt * 32 + (reg & 3) + 8 * (reg >> 2) + 4 * l5;
        float v = acc[mt][nt][reg] + bsv;
        if (MODE == 1) v = gelu_fast(v);
        if (MODE == 4 && gc < 768) v *= 0.125f;
        if (MODE == 2) {
          v += bf2f(ResBf[(size_t)gr * 768 + gc]);
          ((float*)Cout)[(size_t)gr * N + gc] = v;
        } else {
          ((unsigned short*)Cout)[(size_t)gr * N + gc] = f2bf_bits(v);
        }
      }
    }
  }
}

// ---------------------------------------------------------------------------
// V transpose per (b,h): QKV V-cols -> Vt[(b*12+h)*64 + d][4096] bf16
// ---------------------------------------------------------------------------
__global__ __launch_bounds__(256) void vtrans_kernel(
    const unsigned short* __restrict__ Vsrc, unsigned short* __restrict__ Vt) {
  int kb = blockIdx.x, h = blockIdx.y, b = blockIdx.z;
  int k0 = kb * 64;
  const size_t bs = (size_t)b * S_LEN;
  const size_t bh = (size_t)(b * NHEAD + h);
  __shared__ unsigned short tile[64][72];
  int tid = threadIdx.x;
#pragma unroll
  for (int p = 0; p < 2; ++p) {
    int idx = p * 256 + tid;
    int key = idx >> 3, ch = idx & 7;
    bf16x8 v = *(const bf16x8*)(Vsrc + (bs + k0 + key) * QSTR + h * DH + ch * 8);
    *(bf16x8*)&tile[key][ch * 8] = v;
  }
  __syncthreads();
#pragma unroll
  for (int p = 0; p < 2; ++p) {
    int idx = p * 256 + tid;
    int d = idx >> 3, kc = idx & 7;
    unsigned int w0 = tile[kc * 8 + 0][d] | ((unsigned int)tile[kc * 8 + 1][d] << 16);
    unsigned int w1 = tile[kc * 8 + 2][d] | ((unsigned int)tile[kc * 8 + 3][d] << 16);
    unsigned int w2 = tile[kc * 8 + 4][d] | ((unsigned int)tile[kc * 8 + 5][d] << 16);
    unsigned int w3 = tile[kc * 8 + 6][d] | ((unsigned int)tile[kc * 8 + 7][d] << 16);
    uint4 out = make_uint4(w0, w1, w2, w3);
    *(uint4*)(Vt + (bh * 64 + d) * S_LEN + k0 + kc * 8) = out;
  }
}

// ---------------------------------------------------------------------------
// MFMA band attention, half-chunk blocks + double-buffered early-issue K/V.
// grid (33, H=12, B=2), 512 threads = 8 waves x 16 q-rows (128 rows/block).
// c in [0,32): band rows [c*128, c*128+128); c==32: global row 0 full scan.
// Tiles: kb0(t) = c*128 - 256 + t*64, t in [tlo, thi) of 10; K/V staged via
// regs -> swizzled LDS, loads for t+1 issued before compute(t); raw barriers
// + lgkmcnt only (no vmcnt drain in loop).
// ---------------------------------------------------------------------------
__global__ __launch_bounds__(512) void band_attn_kernel(
    const unsigned short* __restrict__ Qg, const unsigned short* __restrict__ Kgb,
    const unsigned short* __restrict__ Vgb, const unsigned short* __restrict__ Vt,
    const int* __restrict__ att, unsigned short* __restrict__ Aout) {
  const int c = blockIdx.x, h = blockIdx.y, b = blockIdx.z;
  const int tid = threadIdx.x;
  const int lane = tid & 63, wq = tid >> 6;
  const int g = lane >> 4, cl = lane & 15;
  const size_t bs = (size_t)b * S_LEN;
  const size_t bh = (size_t)(b * NHEAD + h);

  __shared__ __align__(16) char smem[33280];

  if (c == 32) {
    // ---- global row 0: 512-thread full-S scan ----
    float* sc = (float*)smem;
    float* q0 = sc + S_LEN;
    float* red = q0 + 64;
    float* part = red + 8;
    if (tid < 64) q0[tid] = bf2f(Qg[bs * QSTR + h * DH + tid]);
    __syncthreads();
    float lmax = -1e30f;
    for (int s = tid; s < S_LEN; s += 512) {
      const unsigned short* kp = Kgb + (bs + s) * QSTR + h * DH;
      float acc = 0.f;
#pragma unroll
      for (int cc = 0; cc < 8; ++cc) {
        uint4 u = *(const uint4*)(kp + cc * 8);
        const unsigned int* uu = (const unsigned int*)&u;
#pragma unroll
        for (int w2 = 0; w2 < 4; ++w2) {
          unsigned int x = uu[w2];
          acc += q0[cc * 8 + w2 * 2] * __uint_as_float(x << 16);
          acc += q0[cc * 8 + w2 * 2 + 1] * __uint_as_float(x & 0xffff0000u);
        }
      }
      acc = (att[b * S_LEN + s] > 0) ? acc : -1e9f;
      sc[s] = acc;
      lmax = fmaxf(lmax, acc);
    }
#pragma unroll
    for (int off = 32; off > 0; off >>= 1) lmax = fmaxf(lmax, __shfl_down(lmax, off, 64));
    __syncthreads();
    if (lane == 0) red[wq] = lmax;
    __syncthreads();
    float M = red[0];
#pragma unroll
    for (int i = 1; i < 8; ++i) M = fmaxf(M, red[i]);
    float lsum = 0.f;
    for (int s = tid; s < S_LEN; s += 512) {
      float p = __expf(sc[s] - M);
      sc[s] = p;
      lsum += p;
    }
#pragma unroll
    for (int off = 32; off > 0; off >>= 1) lsum += __shfl_down(lsum, off, 64);
    __syncthreads();
    if (lane == 0) red[wq] = lsum;
    __syncthreads();
    float L = red[0];
#pragma unroll
    for (int i = 1; i < 8; ++i) L += red[i];
    int d = tid & 63, chunk = tid >> 6;
    float acc2 = 0.f;
    for (int s = chunk * 512; s < (chunk + 1) * 512; ++s)
      acc2 += sc[s] * bf2f(Vgb[(bs + s) * QSTR + h * DH + d]);
    part[chunk * 64 + d] = acc2;
    __syncthreads();
    if (tid < 64) {
      float v = 0.f;
#pragma unroll
      for (int i = 0; i < 8; ++i) v += part[i * 64 + tid];
      Aout[bs * D_MODEL + h * DH + tid] = f2bf_bits(v / L);
    }
    return;
  }

  // ---- band path ----
  unsigned short* Klds = (unsigned short*)smem;           // [2][64*64] swizzled
  unsigned short* Vlds = Klds + 2 * 4096;                 // [2][64*64] swizzled
  float* kmask = (float*)(Vlds + 2 * 4096);               // [2][64]

  const int Q0 = c * 128;

  bf16x8 qf[2];
#pragma unroll
  for (int ks = 0; ks < 2; ++ks)
    qf[ks] = *(const bf16x8*)(Qg + (bs + Q0 + wq * 16 + cl) * QSTR +
                              h * DH + ks * 32 + g * 8);

  float mrun, lrun;
  f32x4 oacc[4];
  {
    float sg = 0.f;
#pragma unroll
    for (int ks = 0; ks < 2; ++ks) {
      bf16x8 k0 = *(const bf16x8*)(Kgb + bs * QSTR + h * DH + ks * 32 + g * 8);
#pragma unroll
      for (int j = 0; j < 8; ++j) sg += (float)qf[ks][j] * (float)k0[j];
    }
    sg += __shfl_xor(sg, 16, 64);
    sg += __shfl_xor(sg, 32, 64);
    mrun = sg;
    lrun = 1.f;
#pragma unroll
    for (int dt = 0; dt < 4; ++dt) {
      float v0d = bf2f(Vgb[bs * QSTR + h * DH + dt * 16 + cl]);
      oacc[dt] = (f32x4){v0d, v0d, v0d, v0d};
    }
  }

  const int jwlo = wq * 16, jwhi = wq * 16 + 543;
  const int tlo = (Q0 < 256) ? ((256 - Q0) >> 6) : 0;
  int thi = (S_LEN - Q0 + 256) >> 6;
  if (thi > 10) thi = 10;

  const int skey = tid >> 3, sch = tid & 7;
  const int swz = (sch ^ (skey & 7)) * 8;

  auto LOADT = [&](int t, bf16x8& kr, bf16x8& vr) {
    int kb0 = Q0 - 256 + t * 64;
    kr = *(const bf16x8*)(Kgb + (bs + kb0 + skey) * QSTR + h * DH + sch * 8);
    vr = *(const bf16x8*)(Vt + (bh * 64 + skey) * S_LEN + kb0 + sch * 8);
  };
  auto WRITET = [&](int p, int t, bf16x8 kr, bf16x8 vr) {
    *(bf16x8*)(Klds + p * 4096 + skey * 64 + swz) = kr;
    *(bf16x8*)(Vlds + p * 4096 + skey * 64 + swz) = vr;
    if (tid < 64) {
      int ka = Q0 - 256 + t * 64 + tid;
      kmask[p * 64 + tid] = (ka >= 1 && att[b * S_LEN + ka] > 0) ? 0.f : -1e9f;
    }
  };

  auto COMPUTE = [&](int p, int t) {
    if (t * 64 + 63 < jwlo || t * 64 > jwhi) return;
    f32x4 accs[4];
#pragma unroll
    for (int kt = 0; kt < 4; ++kt) accs[kt] = (f32x4){0.f, 0.f, 0.f, 0.f};
#pragma unroll
    for (int ks = 0; ks < 2; ++ks) {
      bf16x8 kf[4];
#pragma unroll
      for (int kt = 0; kt < 4; ++kt) {
        int key = kt * 16 + cl;
        kf[kt] = *(const bf16x8*)(Klds + p * 4096 + key * 64 +
                                  (((ks * 4 + g) ^ (key & 7)) * 8));
      }
#pragma unroll
      for (int kt = 0; kt < 4; ++kt)
        accs[kt] = MFMA_BF16(kf[kt], qf[ks], accs[kt]);
    }

    int iq = wq * 16 + cl;
    int relbase = t * 64 - iq;
    float pvv[4][4];
    float tmax = -1e30f;
#pragma unroll
    for (int kt = 0; kt < 4; ++kt)
#pragma unroll
      for (int r = 0; r < 4; ++r) {
        int key = kt * 16 + g * 4 + r;
        int rel = relbase + key;
        float x = accs[kt][r] + kmask[p * 64 + key];
        x = (rel >= 0 && rel <= 512) ? x : -1e9f;
        pvv[kt][r] = x;
        tmax = fmaxf(tmax, x);
      }
    tmax = fmaxf(tmax, __shfl_xor(tmax, 16, 64));
    tmax = fmaxf(tmax, __shfl_xor(tmax, 32, 64));
    float mnew = fmaxf(mrun, tmax);
    float scale = __expf(mrun - mnew);
    mrun = mnew;
    float psum = 0.f;
#pragma unroll
    for (int kt = 0; kt < 4; ++kt)
#pragma unroll
      for (int r = 0; r < 4; ++r) {
        float pp = __expf(pvv[kt][r] - mnew);
        pvv[kt][r] = pp;
        psum += pp;
      }
    psum += __shfl_xor(psum, 16, 64);
    psum += __shfl_xor(psum, 32, 64);
    lrun = lrun * scale + psum;
    float scr[4];
#pragma unroll
    for (int r = 0; r < 4; ++r) scr[r] = __shfl(scale, g * 4 + r, 64);
#pragma unroll
    for (int dt = 0; dt < 4; ++dt) {
      oacc[dt][0] *= scr[0];
      oacc[dt][1] *= scr[1];
      oacc[dt][2] *= scr[2];
      oacc[dt][3] *= scr[3];
    }
#pragma unroll
    for (int ks = 0; ks < 2; ++ks) {
      unsigned int E0D0 = cvtpk_bf16(pvv[ks * 2][0], pvv[ks * 2][1]);
      unsigned int E0D1 = cvtpk_bf16(pvv[ks * 2][2], pvv[ks * 2][3]);
      unsigned int E1D0 = cvtpk_bf16(pvv[ks * 2 + 1][0], pvv[ks * 2 + 1][1]);
      unsigned int E1D1 = cvtpk_bf16(pvv[ks * 2 + 1][2], pvv[ks * 2 + 1][3]);
      int src0 = ((lane >> 4) & 1) * 32 + cl;
      int src1 = src0 + 16;
      unsigned int a0 = (unsigned int)__shfl((int)E0D0, src0, 64);
      unsigned int a1 = (unsigned int)__shfl((int)E0D1, src0, 64);
      unsigned int a2 = (unsigned int)__shfl((int)E0D0, src1, 64);
      unsigned int a3 = (unsigned int)__shfl((int)E0D1, src1, 64);
      unsigned int b0 = (unsigned int)__shfl((int)E1D0, src0, 64);
      unsigned int b1 = (unsigned int)__shfl((int)E1D1, src0, 64);
      unsigned int b2 = (unsigned int)__shfl((int)E1D0, src1, 64);
      unsigned int b3 = (unsigned int)__shfl((int)E1D1, src1, 64);
      bool hi = lane >= 32;
      union { unsigned int u[4]; bf16x8 v; } af;
      af.u[0] = hi ? b0 : a0;
      af.u[1] = hi ? b1 : a1;
      af.u[2] = hi ? b2 : a2;
      af.u[3] = hi ? b3 : a3;
#pragma unroll
      for (int dt = 0; dt < 4; ++dt) {
        int d = dt * 16 + cl;
        bf16x8 vf = *(const bf16x8*)(Vlds + p * 4096 + d * 64 +
                                     (((ks * 4 + g) ^ (d & 7)) * 8));
        oacc[dt] = MFMA_BF16(af.v, vf, oacc[dt]);
      }
    }
  };

  bf16x8 kA, vA, kB, vB;
  LOADT(tlo, kA, vA);
  for (int t = tlo; t < thi; t += 2) {
    __builtin_amdgcn_s_barrier();                 // buf0 consumers done
    WRITET(0, t, kA, vA);
    if (t + 1 < thi) LOADT(t + 1, kB, vB);        // early-issue next tile
    asm volatile("s_waitcnt lgkmcnt(0)" ::: "memory");
    __builtin_amdgcn_s_barrier();
    __builtin_amdgcn_sched_barrier(0);
    COMPUTE(0, t);
    if (t + 1 >= thi) break;
    __builtin_amdgcn_s_barrier();                 // buf1 consumers done
    WRITET(1, t + 1, kB, vB);
    if (t + 2 < thi) LOADT(t + 2, kA, vA);
    asm volatile("s_waitcnt lgkmcnt(0)" ::: "memory");
    __builtin_amdgcn_s_barrier();
    __builtin_amdgcn_sched_barrier(0);
    COMPUTE(1, t + 1);
  }

  // write out: row = Q0 + wq*16 + g*4 + r, col = dt*16 + cl
  float lr[4];
#pragma unroll
  for (int r = 0; r < 4; ++r) lr[r] = 1.f / __shfl(lrun, g * 4 + r, 64);
#pragma unroll
  for (int dt = 0; dt < 4; ++dt)
#pragma unroll
    for (int r = 0; r < 4; ++r) {
      int row = Q0 + wq * 16 + g * 4 + r;
      if (row != 0)    // row 0 owned by the global path
        Aout[(bs + row) * D_MODEL + h * DH + dt * 16 + cl] =
            f2bf_bits(oacc[dt][r] * lr[r]);
    }
}

// ---------------------------------------------------------------------------
// masked mean-pool over bf16 X, two stages
// ---------------------------------------------------------------------------
__global__ __launch_bounds__(256) void pool1_kernel(
    const unsigned short* __restrict__ Xb, const int* __restrict__ att,
    float* __restrict__ ppart) {
  int sb = blockIdx.x, b = blockIdx.y, t = threadIdx.x;
  float a0 = 0.f, a1 = 0.f, a2 = 0.f;
  for (int s = sb * 256; s < sb * 256 + 256; ++s) {
    float a = (float)att[b * S_LEN + s];
    const unsigned short* xp = Xb + ((size_t)b * S_LEN + s) * D_MODEL;
    a0 += bf2f(xp[t]) * a; a1 += bf2f(xp[t + 256]) * a; a2 += bf2f(xp[t + 512]) * a;
  }
  float* pp = ppart + ((size_t)b * 16 + sb) * D_MODEL;
  pp[t] = a0; pp[t + 256] = a1; pp[t + 512] = a2;
}

__global__ __launch_bounds__(256) void pool2_kernel(
    const float* __restrict__ ppart, const int* __restrict__ att,
    float* __restrict__ pooled) {
  int b = blockIdx.x, t = threadIdx.x;
  float a0 = 0.f, a1 = 0.f, a2 = 0.f;
  for (int sb = 0; sb < 16; ++sb) {
    const float* pp = ppart + ((size_t)b * 16 + sb) * D_MODEL;
    a0 += pp[t]; a1 += pp[t + 256]; a2 += pp[t + 512];
  }
  float cnt = 0.f;
  for (int s = 0; s < S_LEN; ++s) cnt += (float)att[b * S_LEN + s];
  cnt = fmaxf(cnt, 1e-9f);
  pooled[b * D_MODEL + t]       = a0 / cnt;
  pooled[b * D_MODEL + t + 256] = a1 / cnt;
  pooled[b * D_MODEL + t + 512] = a2 / cnt;
}

// ---------------------------------------------------------------------------
__global__ __launch_bounds__(256) void head_kernel(
    const float* __restrict__ pooled, const float* __restrict__ Wh1,
    const float* __restrict__ bh1, const float* __restrict__ Wh2,
    const float* __restrict__ bh2, float* __restrict__ out) {
  __shared__ float hbuf[2][256];
  int t = threadIdx.x;
  for (int b = 0; b < 2; ++b) {
    float acc = bh1[t];
    for (int d = 0; d < D_MODEL; ++d) acc += pooled[b * D_MODEL + d] * Wh1[d * 256 + t];
    hbuf[b][t] = fmaxf(acc, 0.f);
  }
  __syncthreads();
  if (t < 28) {
    int b = t / 14, j = t % 14;
    float acc = bh2[j];
    for (int i = 0; i < 256; ++i) acc += hbuf[b][i] * Wh2[i * 14 + j];
    out[t] = 4.f / (1.f + __expf(-acc));
  }
}

extern "C" void kernel_launch(void* const* d_in, const int* in_sizes, int n_in,
                              void* d_out, int out_size, void* d_ws,
                              size_t ws_size, hipStream_t stream) {
  const int* ids    = (const int*)d_in[0];
  const int* att    = (const int*)d_in[1];
  const float* wemb = (const float*)d_in[2];
  const float* pemb = (const float*)d_in[3];
  const float* elng = (const float*)d_in[4];
  const float* elnb = (const float*)d_in[5];
  const float* Wq   = (const float*)d_in[6];
  const float* bq   = (const float*)d_in[7];
  const float* Wk   = (const float*)d_in[8];
  const float* bk   = (const float*)d_in[9];
  const float* Wv   = (const float*)d_in[10];
  const float* bv   = (const float*)d_in[11];
  const float* Wo   = (const float*)d_in[12];
  const float* bo   = (const float*)d_in[13];
  const float* ln1g = (const float*)d_in[14];
  const float* ln1b = (const float*)d_in[15];
  const float* Wf1  = (const float*)d_in[16];
  const float* bf1  = (const float*)d_in[17];
  const float* Wf2  = (const float*)d_in[18];
  const float* bf2  = (const float*)d_in[19];
  const float* ln2g = (const float*)d_in[20];
  const float* ln2b = (const float*)d_in[21];
  const float* Wh1  = (const float*)d_in[22];
  const float* bh1  = (const float*)d_in[23];
  const float* Wh2  = (const float*)d_in[24];
  const float* bh2  = (const float*)d_in[25];

  const int M = BATCH * S_LEN;  // 8192
  float* ws = (float*)d_ws;
  float* T = ws;                                            // f32 [0, 6291456)
  unsigned short* QKV  = (unsigned short*)(ws + 6291456);   // 9.44M sh
  unsigned short* Vt   = (unsigned short*)(ws + 11010048);  // 3.15M sh
  unsigned short* Abbf = (unsigned short*)(ws + 12582912);  // 6.29M sh
  unsigned short* Xbf  = (unsigned short*)(ws + 15728640);  // 6.29M sh
  unsigned short* FFbf = (unsigned short*)(ws + 18874368);  // 25.17M sh
  unsigned short* Wbf  = (unsigned short*)(ws + 31457280);  // 14.16M sh
  float* pooled = ws + 38535168;
  float* ppart  = ws + 38536704;

  wconv_kernel<<<13824, 256, 0, stream>>>(Wq, Wk, Wv, Wo, Wf1, Wf2, Wbf);
  embed_ln_kernel<<<M, 256, 0, stream>>>(ids, wemb, pemb, elng, elnb, Xbf);

  for (int l = 0; l < NLAYER; ++l) {
    const unsigned short* wqkv = Wbf + (size_t)l * 7077888;
    const unsigned short* wot  = wqkv + 1769472;
    const unsigned short* wf1t = wqkv + 2359296;
    const unsigned short* wf2t = wqkv + 4718592;

    gemm32<4><<<dim3(18, 64), 256, 0, stream>>>(
        Xbf, wqkv, bq + l * D_MODEL, bk + l * D_MODEL, bv + l * D_MODEL,
        nullptr, QKV, M, QSTR, 768);

    vtrans_kernel<<<dim3(64, NHEAD, BATCH), 256, 0, stream>>>(QKV + 1536, Vt);
    band_attn_kernel<<<dim3(33, NHEAD, BATCH), 512, 0, stream>>>(
        QKV, QKV + 768, QKV + 1536, Vt, att, Abbf);

    gemm32<2><<<dim3(6, 64), 256, 0, stream>>>(
        Abbf, wot, bo + l * D_MODEL, nullptr, nullptr, Xbf, T, M, 768, 768);
    ln_kernel<<<M, 256, 0, stream>>>(T, ln1g + l * D_MODEL, ln1b + l * D_MODEL, Xbf);

    gemm32<1><<<dim3(24, 64), 256, 0, stream>>>(
        Xbf, wf1t, bf1 + l * DFF, nullptr, nullptr, nullptr, FFbf, M, DFF, 768);
    gemm32<2><<<dim3(6, 64), 256, 0, stream>>>(
        FFbf, wf2t, bf2 + l * D_MODEL, nullptr, nullptr, Xbf, T, M, 768, DFF);
    ln_kernel<<<M, 256, 0, stream>>>(T, ln2g + l * D_MODEL, ln2b + l * D_MODEL, Xbf);
  }

  pool1_kernel<<<dim3(16, BATCH), 256, 0, stream>>>(Xbf, att, ppart);
  pool2_kernel<<<BATCH, 256, 0, stream>>>(ppart, att, pooled);
  head_kernel<<<1, 256, 0, stream>>>(pooled, Wh1, bh1, Wh2, bh2, (float*)d_out);
}

// Round 9
// 831.251 us; speedup vs baseline: 1.2009x; 1.2009x over previous
//
#include <hip/hip_runtime.h>
#include <hip/hip_bf16.h>
#include <math.h>

#define S_LEN 4096
#define D_MODEL 768
#define NHEAD 12
#define DH 64
#define NLAYER 2
#define DFF 3072
#define BATCH 2
#define QSTR 2304   // fused QKV row stride

typedef __attribute__((ext_vector_type(8))) __bf16 bf16x8;
typedef __attribute__((ext_vector_type(4))) float f32x4;
typedef __attribute__((ext_vector_type(16))) float f32x16;

__device__ __forceinline__ unsigned short f2bf_bits(float f) {
  unsigned int u = __float_as_uint(f);
  unsigned int r = (u + 0x7fffu + ((u >> 16) & 1u)) >> 16;
  return (unsigned short)r;
}

__device__ __forceinline__ float bf2f(unsigned short u) {
  return __uint_as_float(((unsigned int)u) << 16);
}

__device__ __forceinline__ unsigned int cvtpk_bf16(float lo, float hi) {
  unsigned int d;
  asm("v_cvt_pk_bf16_f32 %0, %1, %2" : "=v"(d) : "v"(lo), "v"(hi));
  return d;
}

// tanh-gelu with cheap tanh via one __expf (clamped)
__device__ __forceinline__ float gelu_fast(float x) {
  float u = 0.7978845608028654f * (x + 0.044715f * x * x * x);
  float t2 = fminf(fmaxf(2.f * u, -18.f), 18.f);
  float e = __expf(t2);
  return 0.5f * x * (1.f + (e - 1.f) / (e + 1.f));
}

#define ASYNC_COPY16(gsrc, ldst)                                       \
  __builtin_amdgcn_global_load_lds(                                    \
      (const __attribute__((address_space(1))) void*)(gsrc),           \
      (__attribute__((address_space(3))) void*)(ldst), 16, 0, 0)

#define MFMA_BF16(a, b, c) __builtin_amdgcn_mfma_f32_16x16x32_bf16(a, b, c, 0, 0, 0)
#define MFMA32_BF16(a, b, c) __builtin_amdgcn_mfma_f32_32x32x16_bf16(a, b, c, 0, 0, 0)

// ---------------------------------------------------------------------------
__device__ __forceinline__ float blk_sum256(float v, float* lds) {
#pragma unroll
  for (int off = 32; off > 0; off >>= 1) v += __shfl_down(v, off, 64);
  __syncthreads();
  if ((threadIdx.x & 63) == 0) lds[threadIdx.x >> 6] = v;
  __syncthreads();
  return lds[0] + lds[1] + lds[2] + lds[3];
}

// ---------------------------------------------------------------------------
// weight transpose + fp32->bf16 convert: W[K][N] f32 -> Wt[N][K] bf16
// ---------------------------------------------------------------------------
__global__ __launch_bounds__(256) void wconv_kernel(
    const float* __restrict__ Wq, const float* __restrict__ Wk,
    const float* __restrict__ Wv, const float* __restrict__ Wo,
    const float* __restrict__ Wf1, const float* __restrict__ Wf2,
    unsigned short* __restrict__ Wbf) {
  int id = blockIdx.x;
  const float* src;
  unsigned short* dst;
  int K, N, t;
  if (id < 4608) {
    int m = id / 576;
    t = id % 576;
    int layer = m >> 2, which = m & 3;
    const float* s = (which == 0) ? Wq : (which == 1) ? Wk : (which == 2) ? Wv : Wo;
    src = s + (size_t)layer * 589824;
    dst = Wbf + (size_t)layer * 7077888 + (size_t)which * 589824;
    K = 768; N = 768;
  } else if (id < 9216) {
    int j = id - 4608;
    int layer = j / 2304;
    t = j % 2304;
    src = Wf1 + (size_t)layer * 2359296;
    dst = Wbf + (size_t)layer * 7077888 + 2359296;
    K = 768; N = 3072;
  } else {
    int j = id - 9216;
    int layer = j / 2304;
    t = j % 2304;
    src = Wf2 + (size_t)layer * 2359296;
    dst = Wbf + (size_t)layer * 7077888 + 4718592;
    K = 3072; N = 768;
  }
  int tiles_n = N >> 5;
  int tk = t / tiles_n, tn = t % tiles_n;
  __shared__ float tile[32][33];
  int c = threadIdx.x & 31, r0 = threadIdx.x >> 5;
#pragma unroll
  for (int p = 0; p < 4; ++p) {
    int r = r0 + p * 8;
    tile[r][c] = src[(size_t)(tk * 32 + r) * N + tn * 32 + c];
  }
  __syncthreads();
#pragma unroll
  for (int p = 0; p < 4; ++p) {
    int r = r0 + p * 8;
    dst[(size_t)(tn * 32 + r) * K + tk * 32 + c] = f2bf_bits(tile[c][r]);
  }
}

// ---------------------------------------------------------------------------
// embedding gather + LayerNorm -> bf16 Xb only
// ---------------------------------------------------------------------------
__global__ __launch_bounds__(256) void embed_ln_kernel(
    const int* __restrict__ ids, const float* __restrict__ wemb,
    const float* __restrict__ pemb, const float* __restrict__ g,
    const float* __restrict__ b, unsigned short* __restrict__ Xb) {
  int row = blockIdx.x;
  int s = row % S_LEN;
  int id = ids[row];
  const float* we = wemb + (size_t)id * D_MODEL;
  const float* pe = pemb + (size_t)s * D_MODEL;
  int t = threadIdx.x;
  __shared__ float lds[4];
  float v0 = we[t] + pe[t];
  float v1 = we[t + 256] + pe[t + 256];
  float v2 = we[t + 512] + pe[t + 512];
  float mean = blk_sum256(v0 + v1 + v2, lds) * (1.f / 768.f);
  float d0 = v0 - mean, d1 = v1 - mean, d2 = v2 - mean;
  float var = blk_sum256(d0 * d0 + d1 * d1 + d2 * d2, lds) * (1.f / 768.f);
  float rs = rsqrtf(var + 1e-5f);
  unsigned short* xb = Xb + (size_t)row * D_MODEL;
  xb[t]       = f2bf_bits(d0 * rs * g[t] + b[t]);
  xb[t + 256] = f2bf_bits(d1 * rs * g[t + 256] + b[t + 256]);
  xb[t + 512] = f2bf_bits(d2 * rs * g[t + 512] + b[t + 512]);
}

// ---------------------------------------------------------------------------
// LayerNorm: Xb = LN(T) * g + b  (T f32 in, bf16 out only)
// ---------------------------------------------------------------------------
__global__ __launch_bounds__(256) void ln_kernel(
    const float* __restrict__ T, const float* __restrict__ g,
    const float* __restrict__ b, unsigned short* __restrict__ Xb) {
  int row = blockIdx.x;
  const float* tp = T + (size_t)row * D_MODEL;
  int t = threadIdx.x;
  __shared__ float lds[4];
  float v0 = tp[t], v1 = tp[t + 256], v2 = tp[t + 512];
  float mean = blk_sum256(v0 + v1 + v2, lds) * (1.f / 768.f);
  float d0 = v0 - mean, d1 = v1 - mean, d2 = v2 - mean;
  float var = blk_sum256(d0 * d0 + d1 * d1 + d2 * d2, lds) * (1.f / 768.f);
  float rs = rsqrtf(var + 1e-5f);
  unsigned short* xb = Xb + (size_t)row * D_MODEL;
  xb[t]       = f2bf_bits(d0 * rs * g[t] + b[t]);
  xb[t + 256] = f2bf_bits(d1 * rs * g[t + 256] + b[t + 256]);
  xb[t + 512] = f2bf_bits(d2 * rs * g[t + 512] + b[t + 512]);
}

// ---------------------------------------------------------------------------
// 32x32x16-MFMA GEMM: 128x128 tile, BK=32, 4 waves (2x2), 3-buf counted
// vmcnt pipeline. C/D: col=lane&31, row=(reg&3)+8*(reg>>2)+4*(lane>>5).
// MODE 1: out bf16, +bias0, gelu           (FFN1)
// MODE 2: out f32, +bias0, +Res bf16       (O-proj / FFN2), N must be 768
// MODE 4: out bf16 stride N, 3 biases, cols<768 scaled 1/8 (QKV)
// ---------------------------------------------------------------------------
template <int MODE>
__global__ __launch_bounds__(256) void gemm32(
    const unsigned short* __restrict__ A, const unsigned short* __restrict__ Bt,
    const float* __restrict__ bias0, const float* __restrict__ bias1,
    const float* __restrict__ bias2, const unsigned short* __restrict__ ResBf,
    void* __restrict__ Cout, int M, int N, int K) {
  __shared__ unsigned short Abuf[3][128 * 32];
  __shared__ unsigned short Bbuf[3][128 * 32];
  const int tid = threadIdx.x;
  const int lane = tid & 63, w = tid >> 6;
  const int wm = w >> 1, wn = w & 1;
  const int l31 = lane & 31, l5 = lane >> 5;

  const int nbx = gridDim.x;
  const int nwg = nbx * gridDim.y;
  const int orig = blockIdx.y * nbx + blockIdx.x;
  const int wgid = (orig & 7) * (nwg >> 3) + (orig >> 3);
  const int m0 = (wgid / nbx) * 128, n0 = (wgid % nbx) * 128;

  f32x16 acc[2][2];
#pragma unroll
  for (int i = 0; i < 2; ++i)
#pragma unroll
    for (int j = 0; j < 2; ++j)
#pragma unroll
      for (int r = 0; r < 16; ++r) acc[i][j][r] = 0.f;

  const int s0 = w * 64 + lane, s1 = s0 + 256;
  const int r0 = s0 >> 2, c0 = (s0 & 3) ^ ((r0 >> 1) & 3);
  const int r1 = s1 >> 2, c1 = (s1 & 3) ^ ((r1 >> 1) & 3);
  const unsigned short* gA0 = A + (size_t)(m0 + r0) * K + c0 * 8;
  const unsigned short* gA1 = A + (size_t)(m0 + r1) * K + c1 * 8;
  const unsigned short* gB0 = Bt + (size_t)(n0 + r0) * K + c0 * 8;
  const unsigned short* gB1 = Bt + (size_t)(n0 + r1) * K + c1 * 8;
  const int dA0 = (w * 64) * 8, dA1 = (256 + w * 64) * 8;

  int aoff[2][2], boff[2][2];
#pragma unroll
  for (int mt = 0; mt < 2; ++mt) {
    int ra = wm * 64 + mt * 32 + l31;
    int rb = wn * 64 + mt * 32 + l31;
    int key_a = (ra >> 1) & 3, key_b = (rb >> 1) & 3;
#pragma unroll
    for (int ks = 0; ks < 2; ++ks) {
      aoff[mt][ks] = ra * 32 + ((((ks << 1) | l5) ^ key_a) << 3);
      boff[mt][ks] = rb * 32 + ((((ks << 1) | l5) ^ key_b) << 3);
    }
  }

#define STAGE(bsel)                                                       \
  {                                                                       \
    ASYNC_COPY16(gA0, &Abuf[bsel][dA0]);                                  \
    ASYNC_COPY16(gA1, &Abuf[bsel][dA1]);                                  \
    ASYNC_COPY16(gB0, &Bbuf[bsel][dA0]);                                  \
    ASYNC_COPY16(gB1, &Bbuf[bsel][dA1]);                                  \
    gA0 += 32; gA1 += 32; gB0 += 32; gB1 += 32;                           \
  }

  const int nk = K >> 5;
  STAGE(0);
  if (nk > 1) STAGE(1);
  asm volatile("s_waitcnt vmcnt(4)" ::: "memory");
  __builtin_amdgcn_s_barrier();
  __builtin_amdgcn_sched_barrier(0);

  int cur = 0;
  for (int kt = 0; kt < nk; ++kt) {
    if (kt + 2 < nk) {
      int nxt = cur + 2;
      if (nxt >= 3) nxt -= 3;
      STAGE(nxt);
    }
    bf16x8 av[2][2], bv[2][2];
#pragma unroll
    for (int mt = 0; mt < 2; ++mt)
#pragma unroll
      for (int ks = 0; ks < 2; ++ks) {
        av[mt][ks] = *(const bf16x8*)(&Abuf[cur][aoff[mt][ks]]);
        bv[mt][ks] = *(const bf16x8*)(&Bbuf[cur][boff[mt][ks]]);
      }
#pragma unroll
    for (int mt = 0; mt < 2; ++mt)
#pragma unroll
      for (int nt = 0; nt < 2; ++nt)
#pragma unroll
        for (int ks = 0; ks < 2; ++ks)
          acc[mt][nt] = MFMA32_BF16(av[mt][ks], bv[nt][ks], acc[mt][nt]);
    if (kt + 1 < nk) {
      if (kt + 2 < nk)
        asm volatile("s_waitcnt vmcnt(4)" ::: "memory");
      else
        asm volatile("s_waitcnt vmcnt(0)" ::: "memory");
      __builtin_amdgcn_s_barrier();
      __builtin_amdgcn_sched_barrier(0);
    }
    cur = (cur == 2) ? 0 : cur + 1;
  }
#undef STAGE

#pragma unroll
  for (int mt = 0; mt < 2; ++mt) {
#pragma unroll
    for (int nt = 0; nt < 2; ++nt) {
      int gc = n0 + wn * 64 + nt * 32 + l31;
      float bsv;
      if (MODE == 4)
        bsv = (gc < 768) ? bias0[gc] : (gc < 1536) ? bias1[gc - 768] : bias2[gc - 1536];
      else
        bsv = bias0[gc];
#pragma unroll
      for (int reg = 0; reg < 16; ++reg) {
        int gr = m0 + wm * 64 + mt * 32 + (reg & 3) + 8 * (reg >> 2) + 4 * l5;
        float v = acc[mt][nt][reg] + bsv;
        if (MODE == 1) v = gelu_fast(v);
        if (MODE == 4 && gc < 768) v *= 0.125f;
        if (MODE == 2) {
          v += bf2f(ResBf[(size_t)gr * 768 + gc]);
          ((float*)Cout)[(size_t)gr * N + gc] = v;
        } else {
          ((unsigned short*)Cout)[(size_t)gr * N + gc] = f2bf_bits(v);
        }
      }
    }
  }
}

// ---------------------------------------------------------------------------
// V transpose per (b,h): QKV V-cols -> Vt[(b*12+h)*64 + d][4096] bf16
// ---------------------------------------------------------------------------
__global__ __launch_bounds__(256) void vtrans_kernel(
    const unsigned short* __restrict__ Vsrc, unsigned short* __restrict__ Vt) {
  int kb = blockIdx.x, h = blockIdx.y, b = blockIdx.z;
  int k0 = kb * 64;
  const size_t bs = (size_t)b * S_LEN;
  const size_t bh = (size_t)(b * NHEAD + h);
  __shared__ unsigned short tile[64][72];
  int tid = threadIdx.x;
#pragma unroll
  for (int p = 0; p < 2; ++p) {
    int idx = p * 256 + tid;
    int key = idx >> 3, ch = idx & 7;
    bf16x8 v = *(const bf16x8*)(Vsrc + (bs + k0 + key) * QSTR + h * DH + ch * 8);
    *(bf16x8*)&tile[key][ch * 8] = v;
  }
  __syncthreads();
#pragma unroll
  for (int p = 0; p < 2; ++p) {
    int idx = p * 256 + tid;
    int d = idx >> 3, kc = idx & 7;
    unsigned int w0 = tile[kc * 8 + 0][d] | ((unsigned int)tile[kc * 8 + 1][d] << 16);
    unsigned int w1 = tile[kc * 8 + 2][d] | ((unsigned int)tile[kc * 8 + 3][d] << 16);
    unsigned int w2 = tile[kc * 8 + 4][d] | ((unsigned int)tile[kc * 8 + 5][d] << 16);
    unsigned int w3 = tile[kc * 8 + 6][d] | ((unsigned int)tile[kc * 8 + 7][d] << 16);
    uint4 out = make_uint4(w0, w1, w2, w3);
    *(uint4*)(Vt + (bh * 64 + d) * S_LEN + k0 + kc * 8) = out;
  }
}

// ---------------------------------------------------------------------------
// MFMA band attention, r7 geometry (256-row chunks, 8 waves x 32 rows) with
// ring-3 global_load_lds staging + depth-2 counted vmcnt + XCD grouping.
// 1D grid 408: bid<384 band (XCD-grouped), bid>=384 global row 0.
// ---------------------------------------------------------------------------
__global__ __launch_bounds__(512) void band_attn_kernel(
    const unsigned short* __restrict__ Qg, const unsigned short* __restrict__ Kgb,
    const unsigned short* __restrict__ Vgb, const unsigned short* __restrict__ Vt,
    const int* __restrict__ att, unsigned short* __restrict__ Aout) {
  const int bid = blockIdx.x;
  const int tid = threadIdx.x;
  const int lane = tid & 63, wq = tid >> 6;
  const int g = lane >> 4, cl = lane & 15;

  __shared__ __align__(16) char smem[52224];

  if (bid >= 384) {
    // ---- global row 0: 512-thread full-S scan ----
    int g2 = bid - 384;
    int h = g2 % NHEAD, b = g2 / NHEAD;
    const size_t bs = (size_t)b * S_LEN;
    float* sc = (float*)smem;
    float* q0 = sc + S_LEN;
    float* red = q0 + 64;
    float* part = red + 8;
    if (tid < 64) q0[tid] = bf2f(Qg[bs * QSTR + h * DH + tid]);
    __syncthreads();
    float lmax = -1e30f;
    for (int s = tid; s < S_LEN; s += 512) {
      const unsigned short* kp = Kgb + (bs + s) * QSTR + h * DH;
      float acc = 0.f;
#pragma unroll
      for (int cc = 0; cc < 8; ++cc) {
        uint4 u = *(const uint4*)(kp + cc * 8);
        const unsigned int* uu = (const unsigned int*)&u;
#pragma unroll
        for (int w2 = 0; w2 < 4; ++w2) {
          unsigned int x = uu[w2];
          acc += q0[cc * 8 + w2 * 2] * __uint_as_float(x << 16);
          acc += q0[cc * 8 + w2 * 2 + 1] * __uint_as_float(x & 0xffff0000u);
        }
      }
      acc = (att[b * S_LEN + s] > 0) ? acc : -1e9f;
      sc[s] = acc;
      lmax = fmaxf(lmax, acc);
    }
#pragma unroll
    for (int off = 32; off > 0; off >>= 1) lmax = fmaxf(lmax, __shfl_down(lmax, off, 64));
    __syncthreads();
    if (lane == 0) red[wq] = lmax;
    __syncthreads();
    float M = red[0];
#pragma unroll
    for (int i = 1; i < 8; ++i) M = fmaxf(M, red[i]);
    float lsum = 0.f;
    for (int s = tid; s < S_LEN; s += 512) {
      float p = __expf(sc[s] - M);
      sc[s] = p;
      lsum += p;
    }
#pragma unroll
    for (int off = 32; off > 0; off >>= 1) lsum += __shfl_down(lsum, off, 64);
    __syncthreads();
    if (lane == 0) red[wq] = lsum;
    __syncthreads();
    float L = red[0];
#pragma unroll
    for (int i = 1; i < 8; ++i) L += red[i];
    int d = tid & 63, chunk = tid >> 6;
    float acc2 = 0.f;
    for (int s = chunk * 512; s < (chunk + 1) * 512; ++s)
      acc2 += sc[s] * bf2f(Vgb[(bs + s) * QSTR + h * DH + d]);
    part[chunk * 64 + d] = acc2;
    __syncthreads();
    if (tid < 64) {
      float v = 0.f;
#pragma unroll
      for (int i = 0; i < 8; ++i) v += part[i * 64 + tid];
      Aout[bs * D_MODEL + h * DH + tid] = f2bf_bits(v / L);
    }
    return;
  }

  // ---- band path: XCD-grouped decode ----
  const int xcd = bid & 7, within = bid >> 3;
  const int flat = xcd * 48 + within;         // 48 = 3 (h,b) groups x 16 chunks
  const int c = flat & 15;
  const int hb = flat >> 4;
  const int h = hb % NHEAD, b = hb / NHEAD;
  const size_t bs = (size_t)b * S_LEN;
  const size_t bh = (size_t)(b * NHEAD + h);

  unsigned short* Klds = (unsigned short*)smem;            // 3 x 4096 shorts
  unsigned short* Vlds = Klds + 3 * 4096;                  // 3 x 4096 shorts
  float* kmaskAll = (float*)(Vlds + 3 * 4096);             // 768 floats

  const int Q0 = c * 256;

  // prologue: Q frags, global-key seed, mask table
  bf16x8 qf[2][2];
#pragma unroll
  for (int qt = 0; qt < 2; ++qt)
#pragma unroll
    for (int ks = 0; ks < 2; ++ks)
      qf[qt][ks] = *(const bf16x8*)(Qg + (bs + Q0 + wq * 32 + qt * 16 + cl) * QSTR +
                                    h * DH + ks * 32 + g * 8);

  float mrun[2], lrun[2];
  f32x4 oacc[2][4];
#pragma unroll
  for (int qt = 0; qt < 2; ++qt) {
    float sg = 0.f;
#pragma unroll
    for (int ks = 0; ks < 2; ++ks) {
      bf16x8 k0 = *(const bf16x8*)(Kgb + bs * QSTR + h * DH + ks * 32 + g * 8);
#pragma unroll
      for (int j = 0; j < 8; ++j) sg += (float)qf[qt][ks][j] * (float)k0[j];
    }
    sg += __shfl_xor(sg, 16, 64);
    sg += __shfl_xor(sg, 32, 64);
    mrun[qt] = sg;
    lrun[qt] = 1.f;
  }
#pragma unroll
  for (int dt = 0; dt < 4; ++dt) {
    float v0d = bf2f(Vgb[bs * QSTR + h * DH + dt * 16 + cl]);
    f32x4 vv = {v0d, v0d, v0d, v0d};
    oacc[0][dt] = vv;
    oacc[1][dt] = vv;
  }
  for (int i = tid; i < 768; i += 512) {
    int ka = Q0 - 256 + i;
    kmaskAll[i] = (ka >= 1 && ka < S_LEN && att[b * S_LEN + ka] > 0) ? 0.f : -1e9f;
  }
  __syncthreads();   // full drain: vmem queue empty, mask table visible

  const int jlo = wq * 32, jhi = wq * 32 + 543;
  const int tlo = (Q0 < 256) ? 4 : 0;
  int thi = (S_LEN + 256 - Q0) >> 6;
  if (thi > 12) thi = 12;

  const int skey = tid >> 3, sch = tid & 7;
  const int srcswzK = (sch ^ (skey & 7)) * 8;   // pre-swizzled source chunk

  auto STAGE_T = [&](int t) {
    int p = t % 3;
    int kb0 = Q0 - 256 + t * 64;
    const unsigned short* srcK = Kgb + (bs + kb0 + skey) * QSTR + h * DH + srcswzK;
    const unsigned short* srcV = Vt + (bh * 64 + skey) * S_LEN + kb0 + srcswzK;
    ASYNC_COPY16(srcK, Klds + p * 4096 + wq * 512);   // dest: wave-uniform + lane*16B
    ASYNC_COPY16(srcV, Vlds + p * 4096 + wq * 512);
  };

  auto COMPUTE = [&](int t) {
    if (t * 64 + 63 < jlo || t * 64 > jhi) return;
    int p = t % 3;
    f32x4 accs[4][2];
#pragma unroll
    for (int kt = 0; kt < 4; ++kt) {
      accs[kt][0] = (f32x4){0.f, 0.f, 0.f, 0.f};
      accs[kt][1] = (f32x4){0.f, 0.f, 0.f, 0.f};
    }
#pragma unroll
    for (int ks = 0; ks < 2; ++ks) {
      bf16x8 kf[4];
#pragma unroll
      for (int kt = 0; kt < 4; ++kt) {
        int key = kt * 16 + cl;
        kf[kt] = *(const bf16x8*)(Klds + p * 4096 + key * 64 +
                                  (((ks * 4 + g) ^ (key & 7)) * 8));
      }
#pragma unroll
      for (int kt = 0; kt < 4; ++kt) {
        accs[kt][0] = MFMA_BF16(kf[kt], qf[0][ks], accs[kt][0]);
        accs[kt][1] = MFMA_BF16(kf[kt], qf[1][ks], accs[kt][1]);
      }
    }

#pragma unroll
    for (int qt = 0; qt < 2; ++qt) {
      int iq = wq * 32 + qt * 16 + cl;
      int relbase = t * 64 - iq;
      float pvv[4][4];
      float tmax = -1e30f;
#pragma unroll
      for (int kt = 0; kt < 4; ++kt)
#pragma unroll
        for (int r = 0; r < 4; ++r) {
          int key = kt * 16 + g * 4 + r;
          int rel = relbase + key;
          float x = accs[kt][qt][r] + kmaskAll[t * 64 + key];
          x = (rel >= 0 && rel <= 512) ? x : -1e9f;
          pvv[kt][r] = x;
          tmax = fmaxf(tmax, x);
        }
      tmax = fmaxf(tmax, __shfl_xor(tmax, 16, 64));
      tmax = fmaxf(tmax, __shfl_xor(tmax, 32, 64));
      float mnew = fmaxf(mrun[qt], tmax);
      float scale = __expf(mrun[qt] - mnew);
      mrun[qt] = mnew;
      float psum = 0.f;
#pragma unroll
      for (int kt = 0; kt < 4; ++kt)
#pragma unroll
        for (int r = 0; r < 4; ++r) {
          float pp = __expf(pvv[kt][r] - mnew);
          pvv[kt][r] = pp;
          psum += pp;
        }
      psum += __shfl_xor(psum, 16, 64);
      psum += __shfl_xor(psum, 32, 64);
      lrun[qt] = lrun[qt] * scale + psum;
      float scr[4];
#pragma unroll
      for (int r = 0; r < 4; ++r) scr[r] = __shfl(scale, g * 4 + r, 64);
#pragma unroll
      for (int dt = 0; dt < 4; ++dt) {
        oacc[qt][dt][0] *= scr[0];
        oacc[qt][dt][1] *= scr[1];
        oacc[qt][dt][2] *= scr[2];
        oacc[qt][dt][3] *= scr[3];
      }
#pragma unroll
      for (int ks = 0; ks < 2; ++ks) {
        unsigned int E0D0 = cvtpk_bf16(pvv[ks * 2][0], pvv[ks * 2][1]);
        unsigned int E0D1 = cvtpk_bf16(pvv[ks * 2][2], pvv[ks * 2][3]);
        unsigned int E1D0 = cvtpk_bf16(pvv[ks * 2 + 1][0], pvv[ks * 2 + 1][1]);
        unsigned int E1D1 = cvtpk_bf16(pvv[ks * 2 + 1][2], pvv[ks * 2 + 1][3]);
        int src0 = ((lane >> 4) & 1) * 32 + cl;
        int src1 = src0 + 16;
        unsigned int a0 = (unsigned int)__shfl((int)E0D0, src0, 64);
        unsigned int a1 = (unsigned int)__shfl((int)E0D1, src0, 64);
        unsigned int a2 = (unsigned int)__shfl((int)E0D0, src1, 64);
        unsigned int a3 = (unsigned int)__shfl((int)E0D1, src1, 64);
        unsigned int b0 = (unsigned int)__shfl((int)E1D0, src0, 64);
        unsigned int b1 = (unsigned int)__shfl((int)E1D1, src0, 64);
        unsigned int b2 = (unsigned int)__shfl((int)E1D0, src1, 64);
        unsigned int b3 = (unsigned int)__shfl((int)E1D1, src1, 64);
        bool hi = lane >= 32;
        union { unsigned int u[4]; bf16x8 v; } af;
        af.u[0] = hi ? b0 : a0;
        af.u[1] = hi ? b1 : a1;
        af.u[2] = hi ? b2 : a2;
        af.u[3] = hi ? b3 : a3;
#pragma unroll
        for (int dt = 0; dt < 4; ++dt) {
          int d = dt * 16 + cl;
          bf16x8 vf = *(const bf16x8*)(Vlds + p * 4096 + d * 64 +
                                       (((ks * 4 + g) ^ (d & 7)) * 8));
          oacc[qt][dt] = MFMA_BF16(af.v, vf, oacc[qt][dt]);
        }
      }
    }
  };

  // ring-3, depth-2 pipeline
  STAGE_T(tlo);
  if (tlo + 1 < thi) STAGE_T(tlo + 1);
  for (int t = tlo; t < thi; ++t) {
    if (t + 1 < thi)
      asm volatile("s_waitcnt vmcnt(2)" ::: "memory");   // tile t landed
    else
      asm volatile("s_waitcnt vmcnt(0)" ::: "memory");
    __builtin_amdgcn_s_barrier();
    __builtin_amdgcn_sched_barrier(0);
    if (t + 2 < thi) STAGE_T(t + 2);
    COMPUTE(t);
  }

  // write out
#pragma unroll
  for (int qt = 0; qt < 2; ++qt) {
    float lr[4];
#pragma unroll
    for (int r = 0; r < 4; ++r) lr[r] = 1.f / __shfl(lrun[qt], g * 4 + r, 64);
#pragma unroll
    for (int dt = 0; dt < 4; ++dt)
#pragma unroll
      for (int r = 0; r < 4; ++r) {
        int row = Q0 + wq * 32 + qt * 16 + g * 4 + r;
        if (row != 0)    // row 0 owned by the global path
          Aout[(bs + row) * D_MODEL + h * DH + dt * 16 + cl] =
              f2bf_bits(oacc[qt][dt][r] * lr[r]);
      }
  }
}

// ---------------------------------------------------------------------------
// masked mean-pool over bf16 X, two stages
// ---------------------------------------------------------------------------
__global__ __launch_bounds__(256) void pool1_kernel(
    const unsigned short* __restrict__ Xb, const int* __restrict__ att,
    float* __restrict__ ppart) {
  int sb = blockIdx.x, b = blockIdx.y, t = threadIdx.x;
  float a0 = 0.f, a1 = 0.f, a2 = 0.f;
  for (int s = sb * 256; s < sb * 256 + 256; ++s) {
    float a = (float)att[b * S_LEN + s];
    const unsigned short* xp = Xb + ((size_t)b * S_LEN + s) * D_MODEL;
    a0 += bf2f(xp[t]) * a; a1 += bf2f(xp[t + 256]) * a; a2 += bf2f(xp[t + 512]) * a;
  }
  float* pp = ppart + ((size_t)b * 16 + sb) * D_MODEL;
  pp[t] = a0; pp[t + 256] = a1; pp[t + 512] = a2;
}

__global__ __launch_bounds__(256) void pool2_kernel(
    const float* __restrict__ ppart, const int* __restrict__ att,
    float* __restrict__ pooled) {
  int b = blockIdx.x, t = threadIdx.x;
  float a0 = 0.f, a1 = 0.f, a2 = 0.f;
  for (int sb = 0; sb < 16; ++sb) {
    const float* pp = ppart + ((size_t)b * 16 + sb) * D_MODEL;
    a0 += pp[t]; a1 += pp[t + 256]; a2 += pp[t + 512];
  }
  float cnt = 0.f;
  for (int s = 0; s < S_LEN; ++s) cnt += (float)att[b * S_LEN + s];
  cnt = fmaxf(cnt, 1e-9f);
  pooled[b * D_MODEL + t]       = a0 / cnt;
  pooled[b * D_MODEL + t + 256] = a1 / cnt;
  pooled[b * D_MODEL + t + 512] = a2 / cnt;
}

// ---------------------------------------------------------------------------
__global__ __launch_bounds__(256) void head_kernel(
    const float* __restrict__ pooled, const float* __restrict__ Wh1,
    const float* __restrict__ bh1, const float* __restrict__ Wh2,
    const float* __restrict__ bh2, float* __restrict__ out) {
  __shared__ float hbuf[2][256];
  int t = threadIdx.x;
  for (int b = 0; b < 2; ++b) {
    float acc = bh1[t];
    for (int d = 0; d < D_MODEL; ++d) acc += pooled[b * D_MODEL + d] * Wh1[d * 256 + t];
    hbuf[b][t] = fmaxf(acc, 0.f);
  }
  __syncthreads();
  if (t < 28) {
    int b = t / 14, j = t % 14;
    float acc = bh2[j];
    for (int i = 0; i < 256; ++i) acc += hbuf[b][i] * Wh2[i * 14 + j];
    out[t] = 4.f / (1.f + __expf(-acc));
  }
}

extern "C" void kernel_launch(void* const* d_in, const int* in_sizes, int n_in,
                              void* d_out, int out_size, void* d_ws,
                              size_t ws_size, hipStream_t stream) {
  const int* ids    = (const int*)d_in[0];
  const int* att    = (const int*)d_in[1];
  const float* wemb = (const float*)d_in[2];
  const float* pemb = (const float*)d_in[3];
  const float* elng = (const float*)d_in[4];
  const float* elnb = (const float*)d_in[5];
  const float* Wq   = (const float*)d_in[6];
  const float* bq   = (const float*)d_in[7];
  const float* Wk   = (const float*)d_in[8];
  const float* bk   = (const float*)d_in[9];
  const float* Wv   = (const float*)d_in[10];
  const float* bv   = (const float*)d_in[11];
  const float* Wo   = (const float*)d_in[12];
  const float* bo   = (const float*)d_in[13];
  const float* ln1g = (const float*)d_in[14];
  const float* ln1b = (const float*)d_in[15];
  const float* Wf1  = (const float*)d_in[16];
  const float* bf1  = (const float*)d_in[17];
  const float* Wf2  = (const float*)d_in[18];
  const float* bf2  = (const float*)d_in[19];
  const float* ln2g = (const float*)d_in[20];
  const float* ln2b = (const float*)d_in[21];
  const float* Wh1  = (const float*)d_in[22];
  const float* bh1  = (const float*)d_in[23];
  const float* Wh2  = (const float*)d_in[24];
  const float* bh2  = (const float*)d_in[25];

  const int M = BATCH * S_LEN;  // 8192
  float* ws = (float*)d_ws;
  float* T = ws;                                            // f32 [0, 6291456)
  unsigned short* QKV  = (unsigned short*)(ws + 6291456);   // 9.44M sh
  unsigned short* Vt   = (unsigned short*)(ws + 11010048);  // 3.15M sh
  unsigned short* Abbf = (unsigned short*)(ws + 12582912);  // 6.29M sh
  unsigned short* Xbf  = (unsigned short*)(ws + 15728640);  // 6.29M sh
  unsigned short* FFbf = (unsigned short*)(ws + 18874368);  // 25.17M sh
  unsigned short* Wbf  = (unsigned short*)(ws + 31457280);  // 14.16M sh
  float* pooled = ws + 38535168;
  float* ppart  = ws + 38536704;

  wconv_kernel<<<13824, 256, 0, stream>>>(Wq, Wk, Wv, Wo, Wf1, Wf2, Wbf);
  embed_ln_kernel<<<M, 256, 0, stream>>>(ids, wemb, pemb, elng, elnb, Xbf);

  for (int l = 0; l < NLAYER; ++l) {
    const unsigned short* wqkv = Wbf + (size_t)l * 7077888;
    const unsigned short* wot  = wqkv + 1769472;
    const unsigned short* wf1t = wqkv + 2359296;
    const unsigned short* wf2t = wqkv + 4718592;

    gemm32<4><<<dim3(18, 64), 256, 0, stream>>>(
        Xbf, wqkv, bq + l * D_MODEL, bk + l * D_MODEL, bv + l * D_MODEL,
        nullptr, QKV, M, QSTR, 768);

    vtrans_kernel<<<dim3(64, NHEAD, BATCH), 256, 0, stream>>>(QKV + 1536, Vt);
    band_attn_kernel<<<408, 512, 0, stream>>>(
        QKV, QKV + 768, QKV + 1536, Vt, att, Abbf);

    gemm32<2><<<dim3(6, 64), 256, 0, stream>>>(
        Abbf, wot, bo + l * D_MODEL, nullptr, nullptr, Xbf, T, M, 768, 768);
    ln_kernel<<<M, 256, 0, stream>>>(T, ln1g + l * D_MODEL, ln1b + l * D_MODEL, Xbf);

    gemm32<1><<<dim3(24, 64), 256, 0, stream>>>(
        Xbf, wf1t, bf1 + l * DFF, nullptr, nullptr, nullptr, FFbf, M, DFF, 768);
    gemm32<2><<<dim3(6, 64), 256, 0, stream>>>(
        FFbf, wf2t, bf2 + l * D_MODEL, nullptr, nullptr, Xbf, T, M, 768, DFF);
    ln_kernel<<<M, 256, 0, stream>>>(T, ln2g + l * D_MODEL, ln2b + l * D_MODEL, Xbf);
  }

  pool1_kernel<<<dim3(16, BATCH), 256, 0, stream>>>(Xbf, att, ppart);
  pool2_kernel<<<BATCH, 256, 0, stream>>>(ppart, att, pooled);
  head_kernel<<<1, 256, 0, stream>>>(pooled, Wh1, bh1, Wh2, bh2, (float*)d_out);
}